// Round 1
// baseline (1424.497 us; speedup 1.0000x reference)
//
#include <hip/hip_runtime.h>
#include <cmath>

#define BB 4
#define SS 256
#define ZDIM 128
#define GCH 256
#define NBLKS 8
#define NPIX 65536   // 256*256
#define U1C 128      // GC/2

__device__ __forceinline__ float lrelu(float x){ return x >= 0.f ? x : 0.2f*x; }

// ---- segment mean pooling (LDS histogram, then global atomics) ----
__global__ void k_pool(const float* __restrict__ img, const int* __restrict__ seg,
                       float* __restrict__ segsum, float* __restrict__ counts){
  __shared__ float ls[SS*4];
  int t = threadIdx.x;
  for(int j=t;j<SS*4;j+=256) ls[j]=0.f;
  __syncthreads();
  int b = blockIdx.x >> 4;           // 16 blocks per batch (4096 px each)
  int base = blockIdx.x*4096;
  for(int it=0; it<16; it++){
    int idx = base + it*256 + t;     // b*N + n
    int n = idx & (NPIX-1);
    int s = seg[idx];
    atomicAdd(&ls[s*4+0], img[(b*3+0)*NPIX+n]);
    atomicAdd(&ls[s*4+1], img[(b*3+1)*NPIX+n]);
    atomicAdd(&ls[s*4+2], img[(b*3+2)*NPIX+n]);
    atomicAdd(&ls[s*4+3], 1.0f);
  }
  __syncthreads();
  for(int j=t;j<SS*4;j+=256){
    int s = j>>2, c = j&3;
    float vv = ls[j];
    if(c<3) atomicAdd(&segsum[(b*SS+s)*3+c], vv);
    else    atomicAdd(&counts[b*SS+s], vv);
  }
}

// ---- transpose A: At[b][j][i] = A[b][i][j] ----
__global__ void k_transA(const float* __restrict__ A, float* __restrict__ At){
  int idx = blockIdx.x*256 + threadIdx.x;
  int b = idx >> 16; int r = idx & 65535; int i = r >> 8; int j = r & 255;
  At[(b*SS + j)*SS + i] = A[idx];
}

// ---- transpose up1_w: wT[(k*256+c)*128+o] = w1[(o*256+c)*9+k] ----
__global__ void k_w1t(const float* __restrict__ w1, float* __restrict__ wT){
  int idx = blockIdx.x*256 + threadIdx.x;   // total 294912
  int o = idx & 127; int r = idx >> 7; int c = r & 255; int k = r >> 8;
  wT[idx] = w1[(o*GCH + c)*9 + k];
}

// ---- x0 = WSproj(concat(feats, z)) : [B,GC,S] ----
__global__ void k_x0(const float* __restrict__ segsum, const float* __restrict__ counts,
                     const float* __restrict__ z, const float* __restrict__ pw,
                     const float* __restrict__ pb, float sc, float* __restrict__ x0){
  int i = blockIdx.x*64 + (threadIdx.x & 63);   // superpixel
  int o = blockIdx.y*4  + (threadIdx.x >> 6);   // out channel
  int b = blockIdx.z;
  float cnt = counts[b*SS+i] + 1e-6f;
  float f0 = segsum[(b*SS+i)*3+0]/cnt;
  float f1 = segsum[(b*SS+i)*3+1]/cnt;
  float f2 = segsum[(b*SS+i)*3+2]/cnt;
  const float* wr = pw + o*131;
  float acc = wr[0]*f0 + wr[1]*f1 + wr[2]*f2;
  const float* zb = z + b*ZDIM;
  for(int j=0;j<ZDIM;j++) acc += wr[3+j]*zb[j];
  x0[(b*GCH+o)*SS + i] = acc*sc + pb[o];
}

// ---- h1 = WS(blk_proj) @ X, X = x0 or leaky(gamma*h2+beta) ----
__global__ void k_gemm1(const float* __restrict__ xin, const float* __restrict__ gb,
                        const float* __restrict__ bw, const float* __restrict__ bb,
                        float sc, float* __restrict__ h1){
  int i = blockIdx.x*64 + (threadIdx.x & 63);
  int c = blockIdx.y*4  + (threadIdx.x >> 6);
  int b = blockIdx.z;
  const float* xb = xin + b*GCH*SS + i;
  const float* wr = bw + c*GCH;
  float acc = 0.f;
  if (gb){
    const float* g = gb + b*512;
    for(int k=0;k<GCH;k++){
      float xv = lrelu(g[k]*xb[k*SS] + g[256+k]);
      acc += wr[k]*xv;
    }
  } else {
    for(int k=0;k<GCH;k++) acc += wr[k]*xb[k*SS];
  }
  h1[(b*GCH+c)*SS + i] = acc*sc + bb[c];
}

// ---- h2[b,c,i] = sum_j At[b,j,i]*h1[b,c,j] ; also m[b,c] = mean_i h2 ----
__global__ void k_gemm2(const float* __restrict__ h1, const float* __restrict__ At,
                        float* __restrict__ h2, float* __restrict__ m){
  int b = blockIdx.x >> 8; int c = blockIdx.x & 255;
  int i = threadIdx.x;
  const float* hr = h1 + (b*GCH+c)*SS;
  const float* ab = At + b*SS*SS + i;
  float acc = 0.f;
  for(int j=0;j<SS;j++) acc += hr[j]*ab[j*SS];
  h2[(b*GCH+c)*SS + i] = acc;
  __shared__ float red[256];
  red[i] = acc; __syncthreads();
  for(int st=128; st>0; st>>=1){ if(i<st) red[i]+=red[i+st]; __syncthreads(); }
  if(i==0) m[b*GCH+c] = red[0]*(1.0f/256.0f);
}

// ---- style: s1 = leaky(WS(ada1)@m), style = WS(ada2)@s1 -> gamma,beta ----
__global__ void k_style(const float* __restrict__ m, const float* __restrict__ a1w,
                        const float* __restrict__ a1b, const float* __restrict__ a2w,
                        const float* __restrict__ a2b, float sc1, float sc2,
                        float* __restrict__ gb){
  int b = blockIdx.x; int t = threadIdx.x;   // 512 threads
  __shared__ float ml[256];
  __shared__ float s1l[512];
  if(t<256) ml[t] = m[b*GCH+t];
  __syncthreads();
  float acc=0.f; const float* wr = a1w + t*GCH;
  for(int k=0;k<GCH;k++) acc += wr[k]*ml[k];
  s1l[t] = lrelu(acc*sc1 + a1b[t]);
  __syncthreads();
  float acc2=0.f; const float* w2r = a2w + t*512;
  for(int k=0;k<512;k++) acc2 += w2r[k]*s1l[k];
  gb[b*512+t] = acc2*sc2 + a2b[t];
}

// ---- final x = leaky(gamma*h2+beta) (elementwise) ----
__global__ void k_xf(const float* __restrict__ h2, const float* __restrict__ gb,
                     float* __restrict__ xf){
  int idx = blockIdx.x*256+threadIdx.x;
  int b = idx >> 16; int c = (idx >> 8) & 255;
  xf[idx] = lrelu(gb[b*512+c]*h2[idx] + gb[b*512+256+c]);
}

// ---- v[b][k][s][o] = sum_c w1[o,c,k] * xf[b,c,s] ----
__global__ void k_v(const float* __restrict__ xf, const float* __restrict__ wT,
                    float* __restrict__ v){
  int o = threadIdx.x & 127; int sl = threadIdx.x >> 7;
  int s = blockIdx.x*2 + sl; int k = blockIdx.y; int b = blockIdx.z;
  const float* xb = xf + b*GCH*SS + s;
  const float* wb = wT + k*GCH*U1C + o;
  float acc = 0.f;
  for(int c=0;c<GCH;c++) acc += wb[c*U1C]*xb[c*SS];
  v[((b*9+k)*SS+s)*U1C + o] = acc;
}

// ---- fused: y1 = leaky(conv1-gather + b1); y2 = conv2(y1)+b2; stats ----
__global__ __launch_bounds__(256) void k_conv(const float* __restrict__ v,
        const int* __restrict__ seg, const float* __restrict__ b1,
        const float* __restrict__ w2, const float* __restrict__ b2,
        float* __restrict__ y2, double* __restrict__ stats){
  __shared__ float y1t[100*129];
  __shared__ int   segl[144];
  __shared__ float part[768];
  int bx = blockIdx.x, by = blockIdx.y, b = blockIdx.z;
  int x0p = bx*8, y0p = by*8;
  int tid = threadIdx.x;
  if(tid < 144){
    int r = tid/12, cc = tid%12;
    int gy = y0p - 2 + r, gx = x0p - 2 + cc;
    segl[tid] = (gy>=0 && gy<256 && gx>=0 && gx<256) ? seg[(b*256+gy)*256+gx] : -1;
  }
  __syncthreads();
  int o = tid & 127;
  const float* vb = v + (size_t)(b*9)*SS*U1C + o;
  float bias = b1[o];
  for(int pp = tid>>7; pp < 100; pp += 2){
    int py = pp/10, px = pp%10;
    int gy = y0p - 1 + py, gx = x0p - 1 + px;
    float val = 0.f;
    if(gy>=0 && gy<256 && gx>=0 && gx<256){
      float acc = bias;
      #pragma unroll
      for(int k=0;k<9;k++){
        int sidx = segl[(py + k/3)*12 + (px + k%3)];
        if(sidx >= 0) acc += vb[(k*SS + sidx)*U1C];
      }
      val = lrelu(acc);
    }
    y1t[pp*129 + o] = val;
  }
  __syncthreads();
  // conv2 on 8x8 tile, 3 out channels, channels split over 4 groups
  int pxo = tid & 63; int cg = tid >> 6;
  int ty = pxo >> 3, tx = pxo & 7;
  float p0=0.f,p1=0.f,p2=0.f;
  for(int k=0;k<9;k++){
    int pp = (ty + k/3)*10 + (tx + k%3);
    const float* yrow = &y1t[pp*129 + cg*32];
    #pragma unroll 8
    for(int cc=0; cc<32; cc++){
      float yv = yrow[cc];
      int c = cg*32 + cc;
      p0 += w2[(0*128+c)*9+k]*yv;
      p1 += w2[(1*128+c)*9+k]*yv;
      p2 += w2[(2*128+c)*9+k]*yv;
    }
  }
  part[tid*3+0]=p0; part[tid*3+1]=p1; part[tid*3+2]=p2;
  __syncthreads();
  if(tid < 64){
    float s0=0.f,s1v=0.f,s2=0.f;
    for(int g=0;g<4;g++){
      s0  += part[(g*64+tid)*3+0];
      s1v += part[(g*64+tid)*3+1];
      s2  += part[(g*64+tid)*3+2];
    }
    s0 += b2[0]; s1v += b2[1]; s2 += b2[2];
    int gy = y0p + (tid>>3), gx = x0p + (tid&7);
    int nidx = gy*256+gx;
    y2[(b*3+0)*NPIX + nidx] = s0;
    y2[(b*3+1)*NPIX + nidx] = s1v;
    y2[(b*3+2)*NPIX + nidx] = s2;
    float v0=s0, v1=s1v, v2=s2, q0=s0*s0, q1=s1v*s1v, q2=s2*s2;
    for(int off=32; off; off>>=1){
      v0 += __shfl_down(v0, off); q0 += __shfl_down(q0, off);
      v1 += __shfl_down(v1, off); q1 += __shfl_down(q1, off);
      v2 += __shfl_down(v2, off); q2 += __shfl_down(q2, off);
    }
    if(tid==0){
      atomicAdd(&stats[(b*3+0)*2+0], (double)v0); atomicAdd(&stats[(b*3+0)*2+1], (double)q0);
      atomicAdd(&stats[(b*3+1)*2+0], (double)v1); atomicAdd(&stats[(b*3+1)*2+1], (double)q1);
      atomicAdd(&stats[(b*3+2)*2+0], (double)v2); atomicAdd(&stats[(b*3+2)*2+1], (double)q2);
    }
  }
}

// ---- instance norm + tanh ----
__global__ void k_norm(const float* __restrict__ y2, const double* __restrict__ stats,
                       float* __restrict__ out){
  int idx = blockIdx.x*256+threadIdx.x;
  int bu = idx >> 16;
  double mu  = stats[bu*2+0] * (1.0/65536.0);
  double ex2 = stats[bu*2+1] * (1.0/65536.0);
  double var = ex2 - mu*mu;
  float inv = (float)(1.0/sqrt(var + 1e-5));
  float mf = (float)mu;
  out[idx] = tanhf((y2[idx]-mf)*inv);
}

extern "C" void kernel_launch(void* const* d_in, const int* in_sizes, int n_in,
                              void* d_out, int out_size, void* d_ws, size_t ws_size,
                              hipStream_t stream) {
  const float* z   = (const float*)d_in[0];
  const float* img = (const float*)d_in[1];
  const int*   seg = (const int*)d_in[2];
  const float* A   = (const float*)d_in[3];
  const float* pw  = (const float*)d_in[4];
  const float* pb  = (const float*)d_in[5];
  const float* bw  = (const float*)d_in[6];
  const float* bb  = (const float*)d_in[7];
  const float* a1w = (const float*)d_in[8];
  const float* a1b = (const float*)d_in[9];
  const float* a2w = (const float*)d_in[10];
  const float* a2b = (const float*)d_in[11];
  const float* w1  = (const float*)d_in[12];
  const float* b1  = (const float*)d_in[13];
  const float* w2  = (const float*)d_in[14];
  const float* b2  = (const float*)d_in[15];
  float* out = (float*)d_out;

  // workspace layout (floats); total ~13.3 MB
  float* ws = (float*)d_ws;
  float* segsum = ws;                 // 3072
  float* counts = ws + 3072;          // 1024
  float* m      = ws + 4096;          // 1024
  float* gb     = ws + 5120;          // 2048
  double* stats = (double*)(ws + 7168); // 24 doubles (48 float slots)
  float* x0 = ws + 7216;              // 262144
  float* h1 = x0 + 262144;
  float* h2 = h1 + 262144;
  float* At = h2 + 262144;
  float* wT = At + 262144;            // 294912
  float* v  = wT + 294912;            // 1179648
  float* y2 = v + 1179648;            // 786432

  hipMemsetAsync(d_ws, 0, 7216*sizeof(float), stream);

  float sProj = (float)sqrt(2.0/131.0);
  float s256  = (float)sqrt(2.0/256.0);
  float s512  = (float)sqrt(2.0/512.0);

  k_pool  <<<64, 256, 0, stream>>>(img, seg, segsum, counts);
  k_transA<<<1024, 256, 0, stream>>>(A, At);
  k_w1t   <<<1152, 256, 0, stream>>>(w1, wT);
  k_x0    <<<dim3(4,64,4), 256, 0, stream>>>(segsum, counts, z, pw, pb, sProj, x0);

  for(int blk=0; blk<NBLKS; blk++){
    k_gemm1<<<dim3(4,64,4), 256, 0, stream>>>(blk==0 ? x0 : h2,
                                              blk==0 ? (const float*)nullptr : gb,
                                              bw + blk*GCH*GCH, bb + blk*GCH, s256, h1);
    k_gemm2<<<1024, 256, 0, stream>>>(h1, At, h2, m);
    k_style<<<4, 512, 0, stream>>>(m, a1w + blk*512*GCH, a1b + blk*512,
                                   a2w + blk*512*512, a2b + blk*512, s256, s512, gb);
  }
  k_xf  <<<1024, 256, 0, stream>>>(h2, gb, x0);
  k_v   <<<dim3(128,9,4), 256, 0, stream>>>(x0, wT, v);
  k_conv<<<dim3(32,32,4), 256, 0, stream>>>(v, seg, b1, w2, b2, y2, stats);
  k_norm<<<3072, 256, 0, stream>>>(y2, stats, out);
}

// Round 2
// 1173.638 us; speedup vs baseline: 1.2137x; 1.2137x over previous
//
#include <hip/hip_runtime.h>
#include <cmath>

#define BB 4
#define SS 256
#define ZDIM 128
#define GCH 256
#define NBLKS 8
#define NPIX 65536   // 256*256
#define U1C 128      // GC/2

__device__ __forceinline__ float lrelu(float x){ return x >= 0.f ? x : 0.2f*x; }

// ---- segment mean pooling (LDS histogram, then global atomics) ----
__global__ void k_pool(const float* __restrict__ img, const int* __restrict__ seg,
                       float* __restrict__ segsum, float* __restrict__ counts){
  __shared__ float ls[SS*4];
  int t = threadIdx.x;
  for(int j=t;j<SS*4;j+=256) ls[j]=0.f;
  __syncthreads();
  int b = blockIdx.x >> 4;
  int base = blockIdx.x*4096;
  for(int it=0; it<16; it++){
    int idx = base + it*256 + t;
    int n = idx & (NPIX-1);
    int s = seg[idx];
    atomicAdd(&ls[s*4+0], img[(b*3+0)*NPIX+n]);
    atomicAdd(&ls[s*4+1], img[(b*3+1)*NPIX+n]);
    atomicAdd(&ls[s*4+2], img[(b*3+2)*NPIX+n]);
    atomicAdd(&ls[s*4+3], 1.0f);
  }
  __syncthreads();
  for(int j=t;j<SS*4;j+=256){
    int s = j>>2, c = j&3;
    float vv = ls[j];
    if(c<3) atomicAdd(&segsum[(b*SS+s)*3+c], vv);
    else    atomicAdd(&counts[b*SS+s], vv);
  }
}

// ---- transpose A: At[b][j][i] = A[b][i][j] ----
__global__ void k_transA(const float* __restrict__ A, float* __restrict__ At){
  int idx = blockIdx.x*256 + threadIdx.x;
  int b = idx >> 16; int r = idx & 65535; int i = r >> 8; int j = r & 255;
  At[(b*SS + j)*SS + i] = A[idx];
}

// ---- transpose up1_w: wT[(k*256+c)*128+o] = w1[(o*256+c)*9+k] ----
__global__ void k_w1t(const float* __restrict__ w1, float* __restrict__ wT){
  int idx = blockIdx.x*256 + threadIdx.x;   // total 294912
  int o = idx & 127; int r = idx >> 7; int c = r & 255; int k = r >> 8;
  wT[idx] = w1[(o*GCH + c)*9 + k];
}

// ---- x0 = WSproj(concat(feats, z)) : [B,GC,S] ----
__global__ void k_x0(const float* __restrict__ segsum, const float* __restrict__ counts,
                     const float* __restrict__ z, const float* __restrict__ pw,
                     const float* __restrict__ pb, float sc, float* __restrict__ x0){
  int i = blockIdx.x*64 + (threadIdx.x & 63);
  int o = blockIdx.y*4  + (threadIdx.x >> 6);
  int b = blockIdx.z;
  float cnt = counts[b*SS+i] + 1e-6f;
  float f0 = segsum[(b*SS+i)*3+0]/cnt;
  float f1 = segsum[(b*SS+i)*3+1]/cnt;
  float f2 = segsum[(b*SS+i)*3+2]/cnt;
  const float* wr = pw + o*131;
  float acc = wr[0]*f0 + wr[1]*f1 + wr[2]*f2;
  const float* zb = z + b*ZDIM;
  for(int j=0;j<ZDIM;j++) acc += wr[3+j]*zb[j];
  x0[(b*GCH+o)*SS + i] = acc*sc + pb[o];
}

// ---- fused graph block: [AdaIN(prev gb)] + gemm1 + A-propagation + node mean ----
// block owns 2 channels (c0, c0+1) of the output; j = node index
__global__ __launch_bounds__(256) void k_blk(const float* __restrict__ xin,
        const float* __restrict__ gb,   // null for blk 0
        const float* __restrict__ bw, const float* __restrict__ bb,
        const float* __restrict__ At, float sc,
        float* __restrict__ h2out, float* __restrict__ m){
  int c0 = blockIdx.x*2;
  int b  = blockIdx.y;
  int j  = threadIdx.x;
  __shared__ float gl[512];
  __shared__ float w0l[256], w1l[256];
  __shared__ float h1l[2][257];
  if(gb){ gl[j] = gb[b*512 + j]; gl[256+j] = gb[b*512 + 256 + j]; }
  w0l[j] = bw[c0*GCH + j];
  w1l[j] = bw[(c0+1)*GCH + j];
  __syncthreads();
  const float* xb = xin + b*GCH*SS + j;
  float a0=0.f, a1=0.f;
  if(gb){
    for(int k=0;k<GCH;k++){
      float xv = lrelu(gl[k]*xb[k*SS] + gl[256+k]);
      a0 += w0l[k]*xv; a1 += w1l[k]*xv;
    }
  } else {
    for(int k=0;k<GCH;k++){ float xv = xb[k*SS]; a0 += w0l[k]*xv; a1 += w1l[k]*xv; }
  }
  h1l[0][j] = a0*sc + bb[c0];
  h1l[1][j] = a1*sc + bb[c0+1];
  __syncthreads();
  const float* ab = At + b*SS*SS + j;
  float r0=0.f, r1=0.f;
  for(int jj=0;jj<SS;jj++){
    float av = ab[jj*SS];
    r0 += h1l[0][jj]*av; r1 += h1l[1][jj]*av;
  }
  h2out[(b*GCH+c0)*SS + j]   = r0;
  h2out[(b*GCH+c0+1)*SS + j] = r1;
  float s0=r0, s1=r1;
  for(int off=32; off; off>>=1){ s0 += __shfl_down(s0,off); s1 += __shfl_down(s1,off); }
  __syncthreads();
  if((j&63)==0){ h1l[0][j>>6] = s0; h1l[1][j>>6] = s1; }
  __syncthreads();
  if(j==0) m[b*GCH+c0]   = (h1l[0][0]+h1l[0][1]+h1l[0][2]+h1l[0][3])*(1.f/256.f);
  if(j==1) m[b*GCH+c0+1] = (h1l[1][0]+h1l[1][1]+h1l[1][2]+h1l[1][3])*(1.f/256.f);
}

// ---- style: s1 = leaky(WS(ada1)@m), style = WS(ada2)@s1 -> gamma,beta ----
__global__ void k_style(const float* __restrict__ m, const float* __restrict__ a1w,
                        const float* __restrict__ a1b, const float* __restrict__ a2w,
                        const float* __restrict__ a2b, float sc1, float sc2,
                        float* __restrict__ gb){
  int b = blockIdx.x; int t = threadIdx.x;   // 512 threads
  __shared__ float ml[256];
  __shared__ float s1l[512];
  if(t<256) ml[t] = m[b*GCH+t];
  __syncthreads();
  float acc=0.f; const float* wr = a1w + t*GCH;
  for(int k=0;k<GCH;k++) acc += wr[k]*ml[k];
  s1l[t] = lrelu(acc*sc1 + a1b[t]);
  __syncthreads();
  float acc2=0.f; const float* w2r = a2w + t*512;
  for(int k=0;k<512;k++) acc2 += w2r[k]*s1l[k];
  gb[b*512+t] = acc2*sc2 + a2b[t];
}

// ---- v[b][k][s][o] = sum_c w1[o,c,k] * lrelu(g*h2+beta) ; AdaIN fused ----
__global__ __launch_bounds__(256) void k_v(const float* __restrict__ h2,
        const float* __restrict__ gb, const float* __restrict__ wT,
        float* __restrict__ v){
  int s0 = blockIdx.x*16;
  int k  = blockIdx.y;
  int b  = blockIdx.z;
  int tid = threadIdx.x;
  __shared__ float gl[512];
  __shared__ float xft[256][17];
  gl[tid] = gb[b*512+tid]; gl[256+tid] = gb[b*512+256+tid];
  __syncthreads();
  for(int t = tid; t < 4096; t += 256){
    int c = t>>4, ss = t&15;
    float xv = h2[(b*GCH+c)*SS + s0 + ss];
    xft[c][ss] = lrelu(gl[c]*xv + gl[256+c]);
  }
  __syncthreads();
  int o = tid & 127, sh = tid >> 7;
  const float* wb = wT + k*GCH*U1C + o;
  float acc[8] = {0,0,0,0,0,0,0,0};
  for(int c=0;c<GCH;c++){
    float wv = wb[c*U1C];
    #pragma unroll
    for(int i=0;i<8;i++) acc[i] += wv * xft[c][sh*8+i];
  }
  float* vout = v + ((size_t)((b*9+k)*SS + s0 + sh*8))*U1C + o;
  #pragma unroll
  for(int i=0;i<8;i++) vout[i*U1C] = acc[i];
}

// ---- fused conv1-gather + conv2 partial (32-channel group), atomic into y2 ----
__global__ __launch_bounds__(256) void k_conv(const float* __restrict__ v,
        const int* __restrict__ seg, const float* __restrict__ b1,
        const float* __restrict__ w2, float* __restrict__ y2){
  __shared__ float y1t[100*33];
  __shared__ int   segl[144];
  __shared__ float w2l[864];
  __shared__ float part[768];
  int x0p = blockIdx.x*8, y0p = blockIdx.y*8;
  int b = blockIdx.z >> 2, g = blockIdx.z & 3;
  int tid = threadIdx.x;
  if(tid < 144){
    int r = tid/12, cc = tid%12;
    int gy = y0p - 2 + r, gx = x0p - 2 + cc;
    segl[tid] = (gy>=0 && gy<256 && gx>=0 && gx<256) ? seg[(b*256+gy)*256+gx] : -1;
  }
  for(int t=tid; t<864; t+=256){
    int oc = t/288, rem = t%288;
    w2l[t] = w2[oc*1152 + g*288 + rem];   // [oc][o32][k] slice for this group
  }
  __syncthreads();
  int o = tid & 31;
  int cgl = g*32 + o;
  const float* vb = v + (size_t)(b*9)*SS*U1C + cgl;
  float bias = b1[cgl];
  for(int pp = tid>>5; pp < 100; pp += 8){
    int py = pp/10, px = pp%10;
    int gy = y0p - 1 + py, gx = x0p - 1 + px;
    float val = 0.f;
    if(gy>=0 && gy<256 && gx>=0 && gx<256){
      float acc = bias;
      #pragma unroll
      for(int k=0;k<9;k++){
        int sidx = segl[(py + k/3)*12 + (px + k%3)];
        if(sidx >= 0) acc += vb[(k*SS + sidx)*U1C];
      }
      val = lrelu(acc);
    }
    y1t[pp*33 + o] = val;
  }
  __syncthreads();
  int pxo = tid & 63, sg = tid >> 6;
  int ty = pxo >> 3, tx = pxo & 7;
  float p0=0.f,p1=0.f,p2=0.f;
  for(int k=0;k<9;k++){
    int pp = (ty + k/3)*10 + (tx + k%3);
    const float* yrow = &y1t[pp*33 + sg*8];
    #pragma unroll
    for(int cc=0;cc<8;cc++){
      float yv = yrow[cc];
      int ci = sg*8+cc;
      p0 += w2l[(0*32+ci)*9+k]*yv;
      p1 += w2l[(1*32+ci)*9+k]*yv;
      p2 += w2l[(2*32+ci)*9+k]*yv;
    }
  }
  part[tid]     = p0;
  part[256+tid] = p1;
  part[512+tid] = p2;
  __syncthreads();
  if(tid < 64){
    float s0 = part[tid]    +part[tid+64]    +part[tid+128]    +part[tid+192];
    float s1 = part[256+tid]+part[256+tid+64]+part[256+tid+128]+part[256+tid+192];
    float s2 = part[512+tid]+part[512+tid+64]+part[512+tid+128]+part[512+tid+192];
    int gy = y0p + (tid>>3), gx = x0p + (tid&7);
    int nidx = gy*256+gx;
    atomicAdd(&y2[(b*3+0)*NPIX+nidx], s0);
    atomicAdd(&y2[(b*3+1)*NPIX+nidx], s1);
    atomicAdd(&y2[(b*3+2)*NPIX+nidx], s2);
  }
}

// ---- per (b,channel) sum & sumsq (conv2 bias cancels under InstanceNorm) ----
__global__ void k_stats(const float* __restrict__ y2, double* __restrict__ stats){
  int bc = blockIdx.x;   // 12
  const float* p = y2 + (size_t)bc*NPIX;
  int t = threadIdx.x;
  double s=0.0, q=0.0;
  for(int i=t;i<NPIX;i+=256){ double vv = (double)p[i]; s+=vv; q+=vv*vv; }
  __shared__ double rs[256], rq[256];
  rs[t]=s; rq[t]=q; __syncthreads();
  for(int st=128; st; st>>=1){ if(t<st){rs[t]+=rs[t+st]; rq[t]+=rq[t+st];} __syncthreads(); }
  if(t==0){ stats[bc*2]=rs[0]; stats[bc*2+1]=rq[0]; }
}

// ---- instance norm + tanh ----
__global__ void k_norm(const float* __restrict__ y2, const double* __restrict__ stats,
                       float* __restrict__ out){
  int idx = blockIdx.x*256+threadIdx.x;
  int bu = idx >> 16;
  double mu  = stats[bu*2+0] * (1.0/65536.0);
  double ex2 = stats[bu*2+1] * (1.0/65536.0);
  double var = ex2 - mu*mu;
  float inv = (float)(1.0/sqrt(var + 1e-5));
  float mf = (float)mu;
  out[idx] = tanhf((y2[idx]-mf)*inv);
}

extern "C" void kernel_launch(void* const* d_in, const int* in_sizes, int n_in,
                              void* d_out, int out_size, void* d_ws, size_t ws_size,
                              hipStream_t stream) {
  const float* z   = (const float*)d_in[0];
  const float* img = (const float*)d_in[1];
  const int*   seg = (const int*)d_in[2];
  const float* A   = (const float*)d_in[3];
  const float* pw  = (const float*)d_in[4];
  const float* pb  = (const float*)d_in[5];
  const float* bw  = (const float*)d_in[6];
  const float* bb  = (const float*)d_in[7];
  const float* a1w = (const float*)d_in[8];
  const float* a1b = (const float*)d_in[9];
  const float* a2w = (const float*)d_in[10];
  const float* a2b = (const float*)d_in[11];
  const float* w1  = (const float*)d_in[12];
  const float* b1  = (const float*)d_in[13];
  const float* w2  = (const float*)d_in[14];
  const float* b2  = (const float*)d_in[15]; (void)b2; // cancels under InstanceNorm
  float* out = (float*)d_out;

  float* ws = (float*)d_ws;
  float* segsum = ws;                  // 3072
  float* counts = ws + 3072;           // 1024
  float* m      = ws + 4096;           // 1024
  float* gb     = ws + 5120;           // 2048
  double* stats = (double*)(ws + 7168);// 24 doubles
  float* x0  = ws + 7216;              // 262144
  float* h2a = x0 + 262144;            // 262144
  float* h2b = h2a + 262144;           // 262144
  float* At  = h2b + 262144;           // 262144
  float* wT  = At + 262144;            // 294912
  float* v   = wT + 294912;            // 1179648
  float* y2  = v + 1179648;            // 786432

  hipMemsetAsync(ws, 0, 4096*sizeof(float), stream);       // segsum+counts
  hipMemsetAsync(y2, 0, 786432*sizeof(float), stream);     // conv2 accumulator

  float sProj = (float)sqrt(2.0/131.0);
  float s256  = (float)sqrt(2.0/256.0);
  float s512  = (float)sqrt(2.0/512.0);

  k_pool  <<<64, 256, 0, stream>>>(img, seg, segsum, counts);
  k_transA<<<1024, 256, 0, stream>>>(A, At);
  k_w1t   <<<1152, 256, 0, stream>>>(w1, wT);
  k_x0    <<<dim3(4,64,4), 256, 0, stream>>>(segsum, counts, z, pw, pb, sProj, x0);

  const float* cur = x0;
  float* nxt = h2a;
  for(int blk=0; blk<NBLKS; blk++){
    k_blk<<<dim3(128,4), 256, 0, stream>>>(cur,
                                           blk==0 ? (const float*)nullptr : gb,
                                           bw + blk*GCH*GCH, bb + blk*GCH,
                                           At, s256, nxt, m);
    k_style<<<4, 512, 0, stream>>>(m, a1w + blk*512*GCH, a1b + blk*512,
                                   a2w + blk*512*512, a2b + blk*512, s256, s512, gb);
    cur = nxt;
    nxt = (nxt == h2a) ? h2b : h2a;
  }

  k_v   <<<dim3(16,9,4), 256, 0, stream>>>(cur, gb, wT, v);
  k_conv<<<dim3(32,32,16), 256, 0, stream>>>(v, seg, b1, w2, y2);
  k_stats<<<12, 256, 0, stream>>>(y2, stats);
  k_norm<<<3072, 256, 0, stream>>>(y2, stats, out);
}

// Round 3
// 880.037 us; speedup vs baseline: 1.6187x; 1.3336x over previous
//
#include <hip/hip_runtime.h>
#include <cmath>

#define BB 4
#define SS 256
#define ZDIM 128
#define GCH 256
#define NBLKS 8
#define NPIX 65536   // 256*256
#define U1C 128      // GC/2

__device__ __forceinline__ float lrelu(float x){ return x >= 0.f ? x : 0.2f*x; }

// ---- segment mean pooling (LDS histogram, then global atomics) ----
__global__ void k_pool(const float* __restrict__ img, const int* __restrict__ seg,
                       float* __restrict__ segsum, float* __restrict__ counts){
  __shared__ float ls[SS*4];
  int t = threadIdx.x;
  for(int j=t;j<SS*4;j+=256) ls[j]=0.f;
  __syncthreads();
  int b = blockIdx.x >> 6;            // 64 blocks per batch (1024 px each)
  int base = blockIdx.x*1024;
  for(int it=0; it<4; it++){
    int idx = base + it*256 + t;
    int n = idx & (NPIX-1);
    int s = seg[idx];
    atomicAdd(&ls[s*4+0], img[(b*3+0)*NPIX+n]);
    atomicAdd(&ls[s*4+1], img[(b*3+1)*NPIX+n]);
    atomicAdd(&ls[s*4+2], img[(b*3+2)*NPIX+n]);
    atomicAdd(&ls[s*4+3], 1.0f);
  }
  __syncthreads();
  for(int j=t;j<SS*4;j+=256){
    int s = j>>2, c = j&3;
    float vv = ls[j];
    if(vv != 0.f){
      if(c<3) atomicAdd(&segsum[(b*SS+s)*3+c], vv);
      else    atomicAdd(&counts[b*SS+s], vv);
    }
  }
}

// ---- prep1: transpose A and up1_w ----
__global__ void k_prep1(const float* __restrict__ A, const float* __restrict__ w1,
                        float* __restrict__ At, float* __restrict__ wT){
  int idx = blockIdx.x*256 + threadIdx.x;   // 262144 + 294912 = 557056
  if(idx < 262144){
    int b = idx >> 16; int r = idx & 65535; int i = r >> 8; int j = r & 255;
    At[(b*SS + j)*SS + i] = A[idx];
  } else {
    int t = idx - 262144;                   // wT[(k*256+c)*128+o] = w1[(o*256+c)*9+k]
    int o = t & 127; int r = t >> 7; int c = r & 255; int k = r >> 8;
    wT[t] = w1[(o*GCH + c)*9 + k];
  }
}

// ---- prep2: transpose ada weights: a1t[blk][k][t]=a1w[blk][t][k], same for a2 ----
__global__ void k_prep2(const float* __restrict__ a1w, const float* __restrict__ a2w,
                        float* __restrict__ a1t, float* __restrict__ a2t){
  int idx = blockIdx.x*256 + threadIdx.x;   // 1048576 + 2097152 = 3145728
  if(idx < 1048576){
    int blk = idx >> 17; int r = idx & 131071; int k = r >> 9; int t = r & 511;
    a1t[idx] = a1w[blk*131072 + t*256 + k];
  } else {
    int i2 = idx - 1048576;
    int blk = i2 >> 18; int r = i2 & 262143; int k = r >> 9; int t = r & 511;
    a2t[i2] = a2w[blk*262144 + t*512 + k];
  }
}

// ---- x0 = WSproj(concat(feats, z)) : [B,GC,S] ----
__global__ void k_x0(const float* __restrict__ segsum, const float* __restrict__ counts,
                     const float* __restrict__ z, const float* __restrict__ pw,
                     const float* __restrict__ pb, float sc, float* __restrict__ x0){
  int i = blockIdx.x*64 + (threadIdx.x & 63);
  int o = blockIdx.y*4  + (threadIdx.x >> 6);
  int b = blockIdx.z;
  float cnt = counts[b*SS+i] + 1e-6f;
  float f0 = segsum[(b*SS+i)*3+0]/cnt;
  float f1 = segsum[(b*SS+i)*3+1]/cnt;
  float f2 = segsum[(b*SS+i)*3+2]/cnt;
  const float* wr = pw + o*131;
  float acc = wr[0]*f0 + wr[1]*f1 + wr[2]*f2;
  const float* zb = z + b*ZDIM;
  for(int j=0;j<ZDIM;j++) acc += wr[3+j]*zb[j];
  x0[(b*GCH+o)*SS + i] = acc*sc + pb[o];
}

// ---- fused graph block: [AdaIN(prev gb)] + gemm1 + A-propagation + node mean ----
// 512 threads: 2 channels per block, 1 channel per thread-half, j = tid&255
__global__ __launch_bounds__(512) void k_blk(const float* __restrict__ xin,
        const float* __restrict__ gb,   // null for blk 0
        const float* __restrict__ bw, const float* __restrict__ bb,
        const float* __restrict__ At, float sc,
        float* __restrict__ h2out, float* __restrict__ m){
  int half = threadIdx.x >> 8;
  int c  = blockIdx.x*2 + half;
  int b  = blockIdx.y;
  int j  = threadIdx.x & 255;
  __shared__ float gl[512];
  __shared__ float wl[2][256];
  __shared__ float red[2][4];
  if(gb) gl[threadIdx.x] = gb[b*512 + threadIdx.x];
  wl[half][j] = bw[c*GCH + j];
  __syncthreads();
  const float* xb = xin + b*GCH*SS + j;
  float a0 = 0.f;
  if(gb){
    #pragma unroll 4
    for(int k=0;k<GCH;k++){
      float xv = lrelu(gl[k]*xb[k*SS] + gl[256+k]);
      a0 += wl[half][k]*xv;
    }
  } else {
    #pragma unroll 4
    for(int k=0;k<GCH;k++) a0 += wl[half][k]*xb[k*SS];
  }
  __shared__ float h1l[2][257];
  h1l[half][j] = a0*sc + bb[c];
  __syncthreads();
  const float* ab = At + b*SS*SS + j;
  float r0 = 0.f;
  #pragma unroll 4
  for(int jj=0;jj<SS;jj++) r0 += h1l[half][jj]*ab[jj*SS];
  h2out[(b*GCH+c)*SS + j] = r0;
  float s0 = r0;
  for(int off=32; off; off>>=1) s0 += __shfl_down(s0, off);
  if((j&63)==0) red[half][j>>6] = s0;
  __syncthreads();
  if(j==0) m[b*GCH+c] = (red[half][0]+red[half][1]+red[half][2]+red[half][3])*(1.f/256.f);
}

// ---- style with transposed weights (coalesced) ----
__global__ void k_styleT(const float* __restrict__ m, const float* __restrict__ a1t,
                         const float* __restrict__ a1b, const float* __restrict__ a2t,
                         const float* __restrict__ a2b, float sc1, float sc2,
                         float* __restrict__ gb){
  int b = blockIdx.x; int t = threadIdx.x;   // 512 threads
  __shared__ float ml[256];
  __shared__ float s1l[512];
  if(t<256) ml[t] = m[b*GCH+t];
  __syncthreads();
  float acc=0.f;
  #pragma unroll 8
  for(int k=0;k<256;k++) acc += a1t[k*512+t]*ml[k];
  s1l[t] = lrelu(acc*sc1 + a1b[t]);
  __syncthreads();
  float acc2=0.f;
  #pragma unroll 8
  for(int k=0;k<512;k++) acc2 += a2t[k*512+t]*s1l[k];
  gb[b*512+t] = acc2*sc2 + a2b[t];
}

// ---- fallback style (untransposed), used if ws too small for a1t/a2t ----
__global__ void k_style(const float* __restrict__ m, const float* __restrict__ a1w,
                        const float* __restrict__ a1b, const float* __restrict__ a2w,
                        const float* __restrict__ a2b, float sc1, float sc2,
                        float* __restrict__ gb){
  int b = blockIdx.x; int t = threadIdx.x;
  __shared__ float ml[256];
  __shared__ float s1l[512];
  if(t<256) ml[t] = m[b*GCH+t];
  __syncthreads();
  float acc=0.f; const float* wr = a1w + t*GCH;
  for(int k=0;k<GCH;k++) acc += wr[k]*ml[k];
  s1l[t] = lrelu(acc*sc1 + a1b[t]);
  __syncthreads();
  float acc2=0.f; const float* w2r = a2w + t*512;
  for(int k=0;k<512;k++) acc2 += w2r[k]*s1l[k];
  gb[b*512+t] = acc2*sc2 + a2b[t];
}

// ---- v[b][k][s][o] = sum_c wT[k][c][o] * lrelu(g*h2+beta) ; AdaIN fused ----
// block: 8 superpixels x (32 float4 channel groups); grid (32, 9, 4)
__global__ __launch_bounds__(256) void k_v(const float* __restrict__ h2,
        const float* __restrict__ gb, const float4* __restrict__ wT4,
        float4* __restrict__ v4){
  int s0 = blockIdx.x*8;
  int k  = blockIdx.y;
  int b  = blockIdx.z;
  int tid = threadIdx.x;
  __shared__ float gl[512];
  __shared__ float xft[256][8];
  gl[tid] = gb[b*512+tid]; gl[256+tid] = gb[b*512+256+tid];
  __syncthreads();
  for(int t = tid; t < 2048; t += 256){
    int c = t>>3, ss = t&7;
    float xv = h2[(b*GCH+c)*SS + s0 + ss];
    xft[c][ss] = lrelu(gl[c]*xv + gl[256+c]);
  }
  __syncthreads();
  int og = tid & 31, s = tid >> 5;
  const float4* wb = wT4 + (size_t)k*GCH*32 + og;
  float4 acc = {0.f,0.f,0.f,0.f};
  #pragma unroll 4
  for(int c=0;c<GCH;c++){
    float xv = xft[c][s];
    float4 w = wb[c*32];
    acc.x += w.x*xv; acc.y += w.y*xv; acc.z += w.z*xv; acc.w += w.w*xv;
  }
  v4[((size_t)(b*9+k)*SS + s0 + s)*32 + og] = acc;
}

// ---- fused conv1-gather(float4) + conv2 partial (32-ch group), atomic y2 ----
__global__ __launch_bounds__(256) void k_conv(const float4* __restrict__ v4,
        const int* __restrict__ seg, const float4* __restrict__ b14,
        const float* __restrict__ w2, float* __restrict__ y2){
  __shared__ float y1t[32*101];     // [ci][pp] transposed
  __shared__ int   segl[144];
  __shared__ float w2l[864];
  __shared__ float part[768];
  int x0p = blockIdx.x*8, y0p = blockIdx.y*8;
  int b = blockIdx.z >> 2, g = blockIdx.z & 3;
  int tid = threadIdx.x;
  if(tid < 144){
    int r = tid/12, cc = tid%12;
    int gy = y0p - 2 + r, gx = x0p - 2 + cc;
    segl[tid] = (gy>=0 && gy<256 && gx>=0 && gx<256) ? seg[(b*256+gy)*256+gx] : -1;
  }
  for(int t=tid; t<864; t+=256){
    int oc = t/288, rem = t%288;
    w2l[t] = w2[oc*1152 + g*288 + rem];
  }
  __syncthreads();
  int o4 = tid & 7;                 // fixed per thread across task iterations
  const float4* vb = v4 + (size_t)(b*9)*SS*32 + g*8 + o4;
  float4 bias = b14[g*8 + o4];
  for(int task = tid; task < 800; task += 256){
    int pp = task >> 3;
    int py = pp/10, px = pp%10;
    int gy = y0p - 1 + py, gx = x0p - 1 + px;
    float4 acc = {0.f,0.f,0.f,0.f};
    if(gy>=0 && gy<256 && gx>=0 && gx<256){
      acc = bias;
      #pragma unroll
      for(int k=0;k<9;k++){
        int sidx = segl[(py + k/3)*12 + (px + k%3)];
        if(sidx >= 0){
          float4 vv = vb[(k*SS + sidx)*32];
          acc.x += vv.x; acc.y += vv.y; acc.z += vv.z; acc.w += vv.w;
        }
      }
      acc.x = lrelu(acc.x); acc.y = lrelu(acc.y); acc.z = lrelu(acc.z); acc.w = lrelu(acc.w);
    }
    int c0 = o4*4;
    y1t[(c0+0)*101+pp] = acc.x;
    y1t[(c0+1)*101+pp] = acc.y;
    y1t[(c0+2)*101+pp] = acc.z;
    y1t[(c0+3)*101+pp] = acc.w;
  }
  __syncthreads();
  int pxo = tid & 63, sg = tid >> 6;
  int ty = pxo >> 3, tx = pxo & 7;
  float p0=0.f,p1=0.f,p2=0.f;
  for(int k=0;k<9;k++){
    int pp0 = (ty + k/3)*10 + (tx + k%3);
    #pragma unroll
    for(int cc=0;cc<8;cc++){
      int ci = sg*8+cc;
      float yv = y1t[ci*101 + pp0];
      p0 += w2l[(0*32+ci)*9+k]*yv;
      p1 += w2l[(1*32+ci)*9+k]*yv;
      p2 += w2l[(2*32+ci)*9+k]*yv;
    }
  }
  part[tid]     = p0;
  part[256+tid] = p1;
  part[512+tid] = p2;
  __syncthreads();
  if(tid < 64){
    float s0 = part[tid]    +part[tid+64]    +part[tid+128]    +part[tid+192];
    float s1 = part[256+tid]+part[256+tid+64]+part[256+tid+128]+part[256+tid+192];
    float s2 = part[512+tid]+part[512+tid+64]+part[512+tid+128]+part[512+tid+192];
    int gy = y0p + (tid>>3), gx = x0p + (tid&7);
    int nidx = gy*256+gx;
    atomicAdd(&y2[(b*3+0)*NPIX+nidx], s0);
    atomicAdd(&y2[(b*3+1)*NPIX+nidx], s1);
    atomicAdd(&y2[(b*3+2)*NPIX+nidx], s2);
  }
}

// ---- per (b,channel) sum & sumsq, parallel chunks with f64 atomics ----
__global__ void k_stats(const float* __restrict__ y2, double* __restrict__ stats){
  int bc = blockIdx.x;     // 12
  int chunk = blockIdx.y;  // 8
  const float* p = y2 + (size_t)bc*NPIX + chunk*8192;
  int t = threadIdx.x;
  double s=0.0, q=0.0;
  for(int i=t;i<8192;i+=256){ double vv = (double)p[i]; s+=vv; q+=vv*vv; }
  __shared__ double rs[256], rq[256];
  rs[t]=s; rq[t]=q; __syncthreads();
  for(int st=128; st; st>>=1){ if(t<st){rs[t]+=rs[t+st]; rq[t]+=rq[t+st];} __syncthreads(); }
  if(t==0){ atomicAdd(&stats[bc*2], rs[0]); atomicAdd(&stats[bc*2+1], rq[0]); }
}

// ---- instance norm + tanh ----
__global__ void k_norm(const float* __restrict__ y2, const double* __restrict__ stats,
                       float* __restrict__ out){
  int idx = blockIdx.x*256+threadIdx.x;
  int bu = idx >> 16;
  double mu  = stats[bu*2+0] * (1.0/65536.0);
  double ex2 = stats[bu*2+1] * (1.0/65536.0);
  double var = ex2 - mu*mu;
  float inv = (float)(1.0/sqrt(var + 1e-5));
  float mf = (float)mu;
  out[idx] = tanhf((y2[idx]-mf)*inv);
}

extern "C" void kernel_launch(void* const* d_in, const int* in_sizes, int n_in,
                              void* d_out, int out_size, void* d_ws, size_t ws_size,
                              hipStream_t stream) {
  const float* z   = (const float*)d_in[0];
  const float* img = (const float*)d_in[1];
  const int*   seg = (const int*)d_in[2];
  const float* A   = (const float*)d_in[3];
  const float* pw  = (const float*)d_in[4];
  const float* pb  = (const float*)d_in[5];
  const float* bw  = (const float*)d_in[6];
  const float* bb  = (const float*)d_in[7];
  const float* a1w = (const float*)d_in[8];
  const float* a1b = (const float*)d_in[9];
  const float* a2w = (const float*)d_in[10];
  const float* a2b = (const float*)d_in[11];
  const float* w1  = (const float*)d_in[12];
  const float* b1  = (const float*)d_in[13];
  const float* w2  = (const float*)d_in[14];
  const float* b2  = (const float*)d_in[15]; (void)b2; // cancels under InstanceNorm
  float* out = (float*)d_out;

  float* ws = (float*)d_ws;
  float* segsum = ws;                  // 3072
  float* counts = ws + 3072;           // 1024
  float* m      = ws + 4096;           // 1024
  float* gb     = ws + 5120;           // 2048
  double* stats = (double*)(ws + 7168);// 24 doubles (48 float slots) -> end 7216
  float* x0  = ws + 7216;              // 262144
  float* h2a = x0 + 262144;
  float* h2b = h2a + 262144;
  float* At  = h2b + 262144;
  float* wT  = At + 262144;            // 294912
  float* v   = wT + 294912;            // 1179648
  float* y2  = v + 1179648;            // 786432
  float* a1t = y2 + 786432;            // 1048576
  float* a2t = a1t + 1048576;          // 2097152
  size_t need = (size_t)(a2t + 2097152 - ws) * sizeof(float);
  bool bigws = ws_size >= need;

  hipMemsetAsync(ws, 0, 7216*sizeof(float), stream);     // sums + stats
  hipMemsetAsync(y2, 0, 786432*sizeof(float), stream);   // conv2 accumulator

  float sProj = (float)sqrt(2.0/131.0);
  float s256  = (float)sqrt(2.0/256.0);
  float s512  = (float)sqrt(2.0/512.0);

  k_pool <<<256, 256, 0, stream>>>(img, seg, segsum, counts);
  k_prep1<<<2176, 256, 0, stream>>>(A, w1, At, wT);
  if(bigws) k_prep2<<<12288, 256, 0, stream>>>(a1w, a2w, a1t, a2t);
  k_x0   <<<dim3(4,64,4), 256, 0, stream>>>(segsum, counts, z, pw, pb, sProj, x0);

  const float* cur = x0;
  float* nxt = h2a;
  for(int blk=0; blk<NBLKS; blk++){
    k_blk<<<dim3(128,4), 512, 0, stream>>>(cur,
                                           blk==0 ? (const float*)nullptr : gb,
                                           bw + blk*GCH*GCH, bb + blk*GCH,
                                           At, s256, nxt, m);
    if(bigws)
      k_styleT<<<4, 512, 0, stream>>>(m, a1t + blk*131072, a1b + blk*512,
                                      a2t + blk*262144, a2b + blk*512, s256, s512, gb);
    else
      k_style<<<4, 512, 0, stream>>>(m, a1w + blk*512*GCH, a1b + blk*512,
                                     a2w + blk*512*512, a2b + blk*512, s256, s512, gb);
    cur = nxt;
    nxt = (nxt == h2a) ? h2b : h2a;
  }

  k_v   <<<dim3(32,9,4), 256, 0, stream>>>(cur, gb, (const float4*)wT, (float4*)v);
  k_conv<<<dim3(32,32,16), 256, 0, stream>>>((const float4*)v, seg, (const float4*)b1, w2, y2);
  k_stats<<<dim3(12,8), 256, 0, stream>>>(y2, stats);
  k_norm<<<3072, 256, 0, stream>>>(y2, stats, out);
}